// Round 20
// baseline (56.383 us; speedup 1.0000x reference)
//
#include <hip/hip_runtime.h>
#include <hip/hip_bf16.h>
#include <float.h>

// Problem constants (B, N, M from the reference)
#define B_      8
#define N_      8192
#define M_      8192
#define NSIDE   (B_ * N_)            // 65536 points per side
#define NTOT    (2 * NSIDE)          // 131072
#define THREADS 256
#define PM      1                    // R20: 1 tile/wave -> small live set, more waves resident
#define BSPLIT  4
#define BCHUNK  (M_ / BSPLIT)        // 2048 b-points per block
#define NTILE   (BCHUNK / 32)        // 64 MFMA b-tiles per block
#define ROWSPB  (4 * PM * 32)        // 128 rows per block (4 waves)
#define NBLOCKS (2 * BSPLIT * (N_ / ROWSPB) * B_)   // 4096

#define BIAS    128.0f               // exact in f16; makes all d' positive

typedef _Float16 f16;
typedef f16   f16x8  __attribute__((ext_vector_type(8)));
typedef float f32x16 __attribute__((ext_vector_type(16)));

// B-pack per point: 16 f16 (32 B) = K-slots (R13/R14 verified + bias slot):
//   k0..7 : [wh, wl, xh, xl, xh, yh, yl, yh]
//   k8..15: [zh, zl, zh, 128, 0, 0, 0, 0]
// Against A rows [1,1,-2xh,-2xh,-2xl,-2yh,-2yh,-2yl | -2zh,-2zh,-2zl,1,0..]:
//   D = 128 + |b|^2 - 2 a.b  (positive: >= 128 - |a|^2 > 0)
// Positive floats order identically as uint bit patterns -> fold with
// umin, which fuses to v_min3_u32 (no NaN semantics) — R19 verified win.
__global__ void prep_kernel(const float* __restrict__ xyz1,
                            const float* __restrict__ xyz2,
                            f16* __restrict__ Bpack,   // [NTOT*16]
                            float* __restrict__ aw,    // [NTOT]
                            float* __restrict__ out,   // [NTOT] -> FLT_MAX
                            int n1, int n_total) {
    int i = blockIdx.x * blockDim.x + threadIdx.x;
    if (i >= n_total) return;
    const float* s = (i < n1) ? (xyz1 + 3 * i) : (xyz2 + 3 * (i - n1));
    float x = s[0], y = s[1], z = s[2];
    float w = fmaf(x, x, fmaf(y, y, z * z));
    f16 xh = (f16)x, yh = (f16)y, zh = (f16)z;
    f16 xl = (f16)(x - (float)xh);
    f16 yl = (f16)(y - (float)yh);
    f16 zl = (f16)(z - (float)zh);
    f16 wh = (f16)w;
    f16 wl = (f16)(w - (float)wh);
    f16x8 b0 = {wh, wl, xh, xl, xh, yh, yl, yh};
    f16x8 b1 = {zh, zl, zh, (f16)BIAS, (f16)0, (f16)0, (f16)0, (f16)0};
    *(f16x8*)(Bpack + (size_t)i * 16 + 0) = b0;
    *(f16x8*)(Bpack + (size_t)i * 16 + 8) = b1;
    aw[i]  = w;
    out[i] = FLT_MAX;                 // atomicMin target (graph-safe re-init)
}

__global__ void init_kernel(float* __restrict__ out, int n) {
    int i = blockIdx.x * blockDim.x + threadIdx.x;
    if (i < n) out[i] = FLT_MAX;
}

static __device__ __forceinline__ unsigned umin2(unsigned a, unsigned b) {
    return a < b ? a : b;
}

// 32x32x16 MFMA main kernel.
// LESSON R15: inline asm must never read MFMA results (silent corruption).
// LESSON R16: extra addressing VALU grows wall 1:1 (linear const offsets only).
// LESSON R17: too many live d-vectors -> AGPR shuffle tax.
// LESSON R18: shrinking per-block WORK while keeping per-block overhead = loss.
// R19 win: unsigned-domain fold (v_min3_u32 fuses legally).
// R20 change: PM=1 (live set ~76 regs incl. MFMA transients, was ~108) +
// launch_bounds(256,6) -> ~6 waves/SIMD resident (was ~4.5 per occupancy
// counter). Work-conserving: 2x blocks x half per-block work; total
// prologue/epilogue/MFMA/fold ops unchanged.
// A operand: row = lane&31, k = (lane>>5)*8 + j.
// B operand: col = lane&31, k = (lane>>5)*8 + j.
// C/D: col = lane&31, row = (reg&3) + 8*(reg>>2) + 4*(lane>>5)  [m74/m101].
__global__ __launch_bounds__(THREADS, 6) void chamfer_mfma32(
    const float* __restrict__ xyz1,
    const float* __restrict__ xyz2,
    const f16*  __restrict__ Bpack,
    const float* __restrict__ aw,
    float* __restrict__ out)
{
    int bid = blockIdx.x;
    int dir   = bid & 1;   bid >>= 1;
    int bs    = bid & (BSPLIT - 1); bid >>= 2;   // log2(BSPLIT)=2
    int ab    = bid & 63;  bid >>= 6;   // N_/128 = 64 a-blocks
    int batch = bid;                    // 0..7

    const int lane = threadIdx.x & 63;
    const int wv   = threadIdx.x >> 6;
    const int g    = lane >> 5;         // k-half 0/1
    const int c    = lane & 31;         // a-row / b-col within tile

    const int aoff = dir ? NSIDE : 0;
    const int boff = dir ? 0 : NSIDE;
    const int abase = batch * N_ + ab * ROWSPB + wv * 32;

    const float* axyz = (dir ? xyz2 : xyz1);

    // ---- A fragment from raw f32 coords (one 32-row tile per wave) ----
    f16x8 af;
    {
        int pa = abase + c;
        const float* s = axyz + 3 * (size_t)pa;
        float x = s[0], y = s[1], z = s[2];
        f16 xh = (f16)x, yh = (f16)y, zh = (f16)z;
        f16 xl = (f16)(x - (float)xh);
        f16 yl = (f16)(y - (float)yh);
        f16 zl = (f16)(z - (float)zh);
        f16 x2 = (f16)(-2.0f * (float)xh), x2l = (f16)(-2.0f * (float)xl);
        f16 y2 = (f16)(-2.0f * (float)yh), y2l = (f16)(-2.0f * (float)yl);
        f16 z2 = (f16)(-2.0f * (float)zh), z2l = (f16)(-2.0f * (float)zl);
        f16x8 lo = {(f16)1.0f, (f16)1.0f, x2, x2, x2l, y2, y2, y2l};
        f16x8 hi = {z2, z2, z2l, (f16)1.0f, (f16)0, (f16)0, (f16)0, (f16)0};
        af = (g == 0) ? lo : hi;
    }

    // ---- B-fragment stream: tile = 32 points x 16 f16 = 1 KB ----
    const f16* Bp = Bpack + (size_t)(boff + batch * M_ + bs * BCHUNK) * 16;
    const f16* blane = Bp + (size_t)c * 16 + g * 8;

    unsigned m[16];
#pragma unroll
    for (int i = 0; i < 16; ++i) m[i] = 0x7F7FFFFFu;  // FLT_MAX bits

    const f32x16 zero16 = {0.f,0.f,0.f,0.f,0.f,0.f,0.f,0.f,
                           0.f,0.f,0.f,0.f,0.f,0.f,0.f,0.f};

    // register prefetch depth 4 tiles; tail over-reads land in aw[] (valid ws)
    f16x8 b0 = *(const f16x8*)(blane + 0 * 512);
    f16x8 b1 = *(const f16x8*)(blane + 1 * 512);
    f16x8 b2 = *(const f16x8*)(blane + 2 * 512);
    f16x8 b3 = *(const f16x8*)(blane + 3 * 512);
    for (int it = 0; it < NTILE; it += 2) {
        f16x8 c0 = b0, c1 = b1;
        b0 = b2; b1 = b3;
        b2 = *(const f16x8*)(blane + (size_t)(it + 4) * 512);
        b3 = *(const f16x8*)(blane + (size_t)(it + 5) * 512);
        f32x16 d0 = __builtin_amdgcn_mfma_f32_32x32x16_f16(af, c0, zero16, 0, 0, 0);
        f32x16 d1 = __builtin_amdgcn_mfma_f32_32x32x16_f16(af, c1, zero16, 0, 0, 0);
#pragma unroll
        for (int i = 0; i < 16; ++i) {
            unsigned u0 = __float_as_uint(d0[i]);
            unsigned u1 = __float_as_uint(d1[i]);
            m[i] = umin2(m[i], umin2(u0, u1));  // -> v_min3_u32 (R19 verified)
        }
    }

    // ---- Reduce min over the 32 col-lanes, then atomicMin ----
    const float* awp = aw + aoff;
    float* o = out + aoff;
#pragma unroll
    for (int s = 1; s < 32; s <<= 1) {
#pragma unroll
        for (int i = 0; i < 16; ++i)
            m[i] = umin2(m[i], (unsigned)__shfl_xor((int)m[i], s));
    }
    // lane c (c<16) takes reg=c via static select chain (no dyn index)
    unsigned uval = m[0];
#pragma unroll
    for (int r = 1; r < 16; ++r) uval = (c == r) ? m[r] : uval;
    if (c < 16) {
        int row = abase + (c & 3) + 8 * (c >> 2) + 4 * g;
        float val = __uint_as_float(uval) - BIAS;     // bias removal exact
        float dd = fmaxf(awp[row] + val, 0.0f);       // clamp keeps uint-min valid
        atomicMin((unsigned int*)(o + row), __float_as_uint(dd));
    }
}

// Fallback if ws too small: raw reads, scalar math (known-good from R2).
#define FP      8
#define FSPLIT  8
#define FCHUNK  (M_ / FSPLIT)
#define FAPB    (THREADS * FP)
#define FATILES (N_ / FAPB)
#define FNBLOCKS (2 * FSPLIT * FATILES * B_)
__global__ __launch_bounds__(THREADS) void chamfer_raw(
    const float* __restrict__ xyz1,
    const float* __restrict__ xyz2,
    float* __restrict__ out)
{
    int bid = blockIdx.x;
    int dir   = bid & 1;                 bid >>= 1;
    int chunk = bid & (FSPLIT - 1);      bid /= FSPLIT;
    int atile = bid & (FATILES - 1);     bid /= FATILES;
    int batch = bid;

    const float* A  = dir ? xyz2 : xyz1;
    const float* Bp = dir ? xyz1 : xyz2;
    float* o = out + (dir ? (B_ * N_) : 0);

    const int a0 = batch * N_ + atile * FAPB + threadIdx.x;

    float ax2[FP], ay2[FP], az2[FP], aww[FP], mm[FP];
#pragma unroll
    for (int p = 0; p < FP; ++p) {
        int idx = a0 + p * THREADS;
        float x = A[3 * idx + 0];
        float y = A[3 * idx + 1];
        float z = A[3 * idx + 2];
        ax2[p] = -2.0f * x;
        ay2[p] = -2.0f * y;
        az2[p] = -2.0f * z;
        aww[p] = fmaf(x, x, fmaf(y, y, z * z));
        mm[p]  = FLT_MAX;
    }

    const float* bp = Bp + 3 * (batch * M_ + chunk * FCHUNK);
#pragma unroll 2
    for (int j = 0; j < FCHUNK; j += 2) {
        float b0x = bp[3 * j + 0], b0y = bp[3 * j + 1], b0z = bp[3 * j + 2];
        float b1x = bp[3 * j + 3], b1y = bp[3 * j + 4], b1z = bp[3 * j + 5];
        float b0w = fmaf(b0x, b0x, fmaf(b0y, b0y, b0z * b0z));
        float b1w = fmaf(b1x, b1x, fmaf(b1y, b1y, b1z * b1z));
#pragma unroll
        for (int p = 0; p < FP; ++p) {
            float t0 = fmaf(ax2[p], b0x, b0w);
            t0 = fmaf(ay2[p], b0y, t0);
            t0 = fmaf(az2[p], b0z, t0);
            float t1 = fmaf(ax2[p], b1x, b1w);
            t1 = fmaf(ay2[p], b1y, t1);
            t1 = fmaf(az2[p], b1z, t1);
            mm[p] = fminf(mm[p], fminf(t0, t1));
        }
    }

#pragma unroll
    for (int p = 0; p < FP; ++p) {
        float d = fmaxf(aww[p] + mm[p], 0.0f);
        atomicMin((unsigned int*)(o + a0 + p * THREADS), __float_as_uint(d));
    }
}

extern "C" void kernel_launch(void* const* d_in, const int* in_sizes, int n_in,
                              void* d_out, int out_size, void* d_ws, size_t ws_size,
                              hipStream_t stream) {
    const float* xyz1 = (const float*)d_in[0];
    const float* xyz2 = (const float*)d_in[1];
    float* out = (float*)d_out;

    // ws layout: Bpack [NTOT*32B] @0, aw [NTOT*4B] after, +16KB pad for
    // prefetch tail over-read (lands in aw, valid memory).
    const size_t bpack_bytes = (size_t)NTOT * 32;
    const size_t need = bpack_bytes + (size_t)NTOT * 4 + 16384;
    if (ws_size >= need) {
        f16*   Bpack = (f16*)d_ws;
        float* aw    = (float*)((char*)d_ws + bpack_bytes);
        prep_kernel<<<(NTOT + 255) / 256, 256, 0, stream>>>(
            xyz1, xyz2, Bpack, aw, out, NSIDE, NTOT);
        chamfer_mfma32<<<NBLOCKS, THREADS, 0, stream>>>(xyz1, xyz2, Bpack, aw, out);
    } else {
        init_kernel<<<(NTOT + 255) / 256, 256, 0, stream>>>(out, NTOT);
        chamfer_raw<<<FNBLOCKS, THREADS, 0, stream>>>(xyz1, xyz2, out);
    }
}

// Round 21
// 49.293 us; speedup vs baseline: 1.1438x; 1.1438x over previous
//
#include <hip/hip_runtime.h>
#include <hip/hip_bf16.h>
#include <float.h>

// Problem constants (B, N, M from the reference)
#define B_      8
#define N_      8192
#define M_      8192
#define NSIDE   (B_ * N_)            // 65536 points per side
#define NTOT    (2 * NSIDE)          // 131072
#define THREADS 256
#define PM      2                    // R19-verified (R20's PM=1 regressed)
#define BSPLIT  4                    // R14/R19-verified
#define BCHUNK  (M_ / BSPLIT)        // 2048 b-points per block
#define NTILE   (BCHUNK / 32)        // 64 MFMA b-tiles per block
#define NBLOCKS (2 * BSPLIT * (N_ / THREADS) * B_)   // 2048

#define BIAS    128.0f               // exact in f16; makes all d' positive

typedef _Float16 f16;
typedef f16   f16x8  __attribute__((ext_vector_type(8)));
typedef float f32x16 __attribute__((ext_vector_type(16)));

// B-pack per point: 16 f16 (32 B) = K-slots (R13/R14 verified + bias slot):
//   k0..7 : [wh, wl, xh, xl, xh, yh, yl, yh]
//   k8..15: [zh, zl, zh, 128, 0, 0, 0, 0]
// Against A rows [1,1,-2xh,-2xh,-2xl,-2yh,-2yh,-2yl | -2zh,-2zh,-2zl,1,0..]:
//   D = 128 + |b|^2 - 2 a.b  (positive: >= 128 - |a|^2 > 0)
// Positive floats order identically as uint bit patterns -> fold with
// umin, which fuses to v_min3_u32 (no NaN semantics) — R19 verified win.
__global__ void prep_kernel(const float* __restrict__ xyz1,
                            const float* __restrict__ xyz2,
                            f16* __restrict__ Bpack,   // [NTOT*16]
                            float* __restrict__ aw,    // [NTOT]
                            float* __restrict__ out,   // [NTOT] -> FLT_MAX
                            int n1, int n_total) {
    int i = blockIdx.x * blockDim.x + threadIdx.x;
    if (i >= n_total) return;
    const float* s = (i < n1) ? (xyz1 + 3 * i) : (xyz2 + 3 * (i - n1));
    float x = s[0], y = s[1], z = s[2];
    float w = fmaf(x, x, fmaf(y, y, z * z));
    f16 xh = (f16)x, yh = (f16)y, zh = (f16)z;
    f16 xl = (f16)(x - (float)xh);
    f16 yl = (f16)(y - (float)yh);
    f16 zl = (f16)(z - (float)zh);
    f16 wh = (f16)w;
    f16 wl = (f16)(w - (float)wh);
    f16x8 b0 = {wh, wl, xh, xl, xh, yh, yl, yh};
    f16x8 b1 = {zh, zl, zh, (f16)BIAS, (f16)0, (f16)0, (f16)0, (f16)0};
    *(f16x8*)(Bpack + (size_t)i * 16 + 0) = b0;
    *(f16x8*)(Bpack + (size_t)i * 16 + 8) = b1;
    aw[i]  = w;
    out[i] = FLT_MAX;                 // atomicMin target (graph-safe re-init)
}

__global__ void init_kernel(float* __restrict__ out, int n) {
    int i = blockIdx.x * blockDim.x + threadIdx.x;
    if (i < n) out[i] = FLT_MAX;
}

static __device__ __forceinline__ unsigned umin2(unsigned a, unsigned b) {
    return a < b ? a : b;
}

// 32x32x16 MFMA main kernel — R19 structure VERBATIM except launch bounds.
// LESSON R15: inline asm must never read MFMA results (silent corruption).
// LESSON R16: extra addressing VALU grows wall 1:1 (linear const offsets only).
// LESSON R17: too many live d-vectors -> AGPR shuffle tax.
// LESSON R18/R20: changing block/work split away from R14's shape = loss.
// R19 win: unsigned-domain fold (v_min3_u32 fuses legally).
// R21 probe: __launch_bounds__(256,2) (VGPR cap 256, was 128). R19 showed
// VGPR_Count=44 + Occupancy 37% ==> the 64-reg MFMA accumulator set lives in
// AGPRs and every fold operand transits v_accvgpr_read (~27k cyc/SIMD of
// unexplained VALU). With a 256-reg budget the allocator has no pressure
// reason to split the ~110-reg working set across the acc file. Resident
// waves unchanged (footprint-bound at ~4.6/SIMD) — isolates transfer cost.
// A operand: row = lane&31, k = (lane>>5)*8 + j.
// B operand: col = lane&31, k = (lane>>5)*8 + j.
// C/D: col = lane&31, row = (reg&3) + 8*(reg>>2) + 4*(lane>>5)  [m74/m101].
__global__ __launch_bounds__(THREADS, 2) void chamfer_mfma32(
    const float* __restrict__ xyz1,
    const float* __restrict__ xyz2,
    const f16*  __restrict__ Bpack,
    const float* __restrict__ aw,
    float* __restrict__ out)
{
    int bid = blockIdx.x;
    int dir   = bid & 1;   bid >>= 1;
    int bs    = bid & (BSPLIT - 1); bid >>= 2;   // log2(BSPLIT)=2
    int ab    = bid & 31;  bid >>= 5;   // N_/256 = 32 a-blocks
    int batch = bid;                    // 0..7

    const int lane = threadIdx.x & 63;
    const int wv   = threadIdx.x >> 6;
    const int g    = lane >> 5;         // k-half 0/1
    const int c    = lane & 31;         // a-row / b-col within tile

    const int aoff = dir ? NSIDE : 0;
    const int boff = dir ? 0 : NSIDE;
    const int abase = batch * N_ + ab * THREADS + wv * (PM * 32);

    const float* axyz = (dir ? xyz2 : xyz1);

    // ---- A fragments from raw f32 coords ----
    f16x8 af[PM];
#pragma unroll
    for (int t = 0; t < PM; ++t) {
        int pa = abase + t * 32 + c;
        const float* s = axyz + 3 * (size_t)pa;
        float x = s[0], y = s[1], z = s[2];
        f16 xh = (f16)x, yh = (f16)y, zh = (f16)z;
        f16 xl = (f16)(x - (float)xh);
        f16 yl = (f16)(y - (float)yh);
        f16 zl = (f16)(z - (float)zh);
        f16 x2 = (f16)(-2.0f * (float)xh), x2l = (f16)(-2.0f * (float)xl);
        f16 y2 = (f16)(-2.0f * (float)yh), y2l = (f16)(-2.0f * (float)yl);
        f16 z2 = (f16)(-2.0f * (float)zh), z2l = (f16)(-2.0f * (float)zl);
        f16x8 lo = {(f16)1.0f, (f16)1.0f, x2, x2, x2l, y2, y2, y2l};
        f16x8 hi = {z2, z2, z2l, (f16)1.0f, (f16)0, (f16)0, (f16)0, (f16)0};
        af[t] = (g == 0) ? lo : hi;
    }

    // ---- B-fragment stream: tile = 32 points x 16 f16 = 1 KB ----
    const f16* Bp = Bpack + (size_t)(boff + batch * M_ + bs * BCHUNK) * 16;
    const f16* blane = Bp + (size_t)c * 16 + g * 8;

    unsigned m[PM][16];
#pragma unroll
    for (int t = 0; t < PM; ++t)
#pragma unroll
        for (int i = 0; i < 16; ++i) m[t][i] = 0x7F7FFFFFu;  // FLT_MAX bits

    const f32x16 zero16 = {0.f,0.f,0.f,0.f,0.f,0.f,0.f,0.f,
                           0.f,0.f,0.f,0.f,0.f,0.f,0.f,0.f};

    // register prefetch depth 4 tiles; tail over-reads land in aw[] (valid ws)
    f16x8 b0 = *(const f16x8*)(blane + 0 * 512);
    f16x8 b1 = *(const f16x8*)(blane + 1 * 512);
    f16x8 b2 = *(const f16x8*)(blane + 2 * 512);
    f16x8 b3 = *(const f16x8*)(blane + 3 * 512);
    for (int it = 0; it < NTILE; it += 2) {
        f16x8 c0 = b0, c1 = b1;
        b0 = b2; b1 = b3;
        b2 = *(const f16x8*)(blane + (size_t)(it + 4) * 512);
        b3 = *(const f16x8*)(blane + (size_t)(it + 5) * 512);
#pragma unroll
        for (int t = 0; t < PM; ++t) {
            f32x16 d0 = __builtin_amdgcn_mfma_f32_32x32x16_f16(af[t], c0, zero16, 0, 0, 0);
            f32x16 d1 = __builtin_amdgcn_mfma_f32_32x32x16_f16(af[t], c1, zero16, 0, 0, 0);
#pragma unroll
            for (int i = 0; i < 16; ++i) {
                unsigned u0 = __float_as_uint(d0[i]);
                unsigned u1 = __float_as_uint(d1[i]);
                m[t][i] = umin2(m[t][i], umin2(u0, u1));  // -> v_min3_u32
            }
        }
    }

    // ---- Reduce min over the 32 col-lanes, then atomicMin ----
    const float* awp = aw + aoff;
    float* o = out + aoff;
#pragma unroll
    for (int t = 0; t < PM; ++t) {
        unsigned mm[16];
#pragma unroll
        for (int i = 0; i < 16; ++i) mm[i] = m[t][i];
#pragma unroll
        for (int s = 1; s < 32; s <<= 1) {
#pragma unroll
            for (int i = 0; i < 16; ++i)
                mm[i] = umin2(mm[i], (unsigned)__shfl_xor((int)mm[i], s));
        }
        // lane c (c<16) takes reg=c via static select chain (no dyn index)
        unsigned uval = mm[0];
#pragma unroll
        for (int r = 1; r < 16; ++r) uval = (c == r) ? mm[r] : uval;
        if (c < 16) {
            int row = abase + t * 32 + (c & 3) + 8 * (c >> 2) + 4 * g;
            float val = __uint_as_float(uval) - BIAS;     // bias removal exact
            float dd = fmaxf(awp[row] + val, 0.0f);       // clamp keeps uint-min valid
            atomicMin((unsigned int*)(o + row), __float_as_uint(dd));
        }
    }
}

// Fallback if ws too small: raw reads, scalar math (known-good from R2).
#define FP      8
#define FSPLIT  8
#define FCHUNK  (M_ / FSPLIT)
#define FAPB    (THREADS * FP)
#define FATILES (N_ / FAPB)
#define FNBLOCKS (2 * FSPLIT * FATILES * B_)
__global__ __launch_bounds__(THREADS) void chamfer_raw(
    const float* __restrict__ xyz1,
    const float* __restrict__ xyz2,
    float* __restrict__ out)
{
    int bid = blockIdx.x;
    int dir   = bid & 1;                 bid >>= 1;
    int chunk = bid & (FSPLIT - 1);      bid /= FSPLIT;
    int atile = bid & (FATILES - 1);     bid /= FATILES;
    int batch = bid;

    const float* A  = dir ? xyz2 : xyz1;
    const float* Bp = dir ? xyz1 : xyz2;
    float* o = out + (dir ? (B_ * N_) : 0);

    const int a0 = batch * N_ + atile * FAPB + threadIdx.x;

    float ax2[FP], ay2[FP], az2[FP], aww[FP], mm[FP];
#pragma unroll
    for (int p = 0; p < FP; ++p) {
        int idx = a0 + p * THREADS;
        float x = A[3 * idx + 0];
        float y = A[3 * idx + 1];
        float z = A[3 * idx + 2];
        ax2[p] = -2.0f * x;
        ay2[p] = -2.0f * y;
        az2[p] = -2.0f * z;
        aww[p] = fmaf(x, x, fmaf(y, y, z * z));
        mm[p]  = FLT_MAX;
    }

    const float* bp = Bp + 3 * (batch * M_ + chunk * FCHUNK);
#pragma unroll 2
    for (int j = 0; j < FCHUNK; j += 2) {
        float b0x = bp[3 * j + 0], b0y = bp[3 * j + 1], b0z = bp[3 * j + 2];
        float b1x = bp[3 * j + 3], b1y = bp[3 * j + 4], b1z = bp[3 * j + 5];
        float b0w = fmaf(b0x, b0x, fmaf(b0y, b0y, b0z * b0z));
        float b1w = fmaf(b1x, b1x, fmaf(b1y, b1y, b1z * b1z));
#pragma unroll
        for (int p = 0; p < FP; ++p) {
            float t0 = fmaf(ax2[p], b0x, b0w);
            t0 = fmaf(ay2[p], b0y, t0);
            t0 = fmaf(az2[p], b0z, t0);
            float t1 = fmaf(ax2[p], b1x, b1w);
            t1 = fmaf(ay2[p], b1y, t1);
            t1 = fmaf(az2[p], b1z, t1);
            mm[p] = fminf(mm[p], fminf(t0, t1));
        }
    }

#pragma unroll
    for (int p = 0; p < FP; ++p) {
        float d = fmaxf(aww[p] + mm[p], 0.0f);
        atomicMin((unsigned int*)(o + a0 + p * THREADS), __float_as_uint(d));
    }
}

extern "C" void kernel_launch(void* const* d_in, const int* in_sizes, int n_in,
                              void* d_out, int out_size, void* d_ws, size_t ws_size,
                              hipStream_t stream) {
    const float* xyz1 = (const float*)d_in[0];
    const float* xyz2 = (const float*)d_in[1];
    float* out = (float*)d_out;

    // ws layout: Bpack [NTOT*32B] @0, aw [NTOT*4B] after, +16KB pad for
    // prefetch tail over-read (lands in aw, valid memory).
    const size_t bpack_bytes = (size_t)NTOT * 32;
    const size_t need = bpack_bytes + (size_t)NTOT * 4 + 16384;
    if (ws_size >= need) {
        f16*   Bpack = (f16*)d_ws;
        float* aw    = (float*)((char*)d_ws + bpack_bytes);
        prep_kernel<<<(NTOT + 255) / 256, 256, 0, stream>>>(
            xyz1, xyz2, Bpack, aw, out, NSIDE, NTOT);
        chamfer_mfma32<<<NBLOCKS, THREADS, 0, stream>>>(xyz1, xyz2, Bpack, aw, out);
    } else {
        init_kernel<<<(NTOT + 255) / 256, 256, 0, stream>>>(out, NTOT);
        chamfer_raw<<<FNBLOCKS, THREADS, 0, stream>>>(xyz1, xyz2, out);
    }
}

// Round 22
// 47.517 us; speedup vs baseline: 1.1866x; 1.0374x over previous
//
#include <hip/hip_runtime.h>
#include <hip/hip_bf16.h>
#include <float.h>

// Problem constants (B, N, M from the reference)
#define B_      8
#define N_      8192
#define M_      8192
#define NSIDE   (B_ * N_)            // 65536 points per side
#define NTOT    (2 * NSIDE)          // 131072
#define THREADS 256
#define PM      2                    // R19-verified (R20's PM=1 regressed)
#define BSPLIT  2                    // R22: 4->2. Halve epilogue replicas;
                                     // 1024 blocks = exactly 4/CU (matches
                                     // the ~4.6-wave footprint residency)
#define BCHUNK  (M_ / BSPLIT)        // 4096 b-points per block
#define NTILE   (BCHUNK / 32)        // 128 MFMA b-tiles per block
#define NBLOCKS (2 * BSPLIT * (N_ / THREADS) * B_)   // 1024

#define BIAS    128.0f               // exact in f16; makes all d' positive

typedef _Float16 f16;
typedef f16   f16x8  __attribute__((ext_vector_type(8)));
typedef float f32x16 __attribute__((ext_vector_type(16)));

// B-pack per point: 16 f16 (32 B) = K-slots (R13/R14 verified + bias slot):
//   k0..7 : [wh, wl, xh, xl, xh, yh, yl, yh]
//   k8..15: [zh, zl, zh, 128, 0, 0, 0, 0]
// Against A rows [1,1,-2xh,-2xh,-2xl,-2yh,-2yh,-2yl | -2zh,-2zh,-2zl,1,0..]:
//   D = 128 + |b|^2 - 2 a.b  (positive: >= 128 - |a|^2 > 0)
// Positive floats order identically as uint bit patterns -> fold with
// umin, which fuses to v_min3_u32 (no NaN semantics) — R19 verified win.
__global__ void prep_kernel(const float* __restrict__ xyz1,
                            const float* __restrict__ xyz2,
                            f16* __restrict__ Bpack,   // [NTOT*16]
                            float* __restrict__ aw,    // [NTOT]
                            float* __restrict__ out,   // [NTOT] -> FLT_MAX
                            int n1, int n_total) {
    int i = blockIdx.x * blockDim.x + threadIdx.x;
    if (i >= n_total) return;
    const float* s = (i < n1) ? (xyz1 + 3 * i) : (xyz2 + 3 * (i - n1));
    float x = s[0], y = s[1], z = s[2];
    float w = fmaf(x, x, fmaf(y, y, z * z));
    f16 xh = (f16)x, yh = (f16)y, zh = (f16)z;
    f16 xl = (f16)(x - (float)xh);
    f16 yl = (f16)(y - (float)yh);
    f16 zl = (f16)(z - (float)zh);
    f16 wh = (f16)w;
    f16 wl = (f16)(w - (float)wh);
    f16x8 b0 = {wh, wl, xh, xl, xh, yh, yl, yh};
    f16x8 b1 = {zh, zl, zh, (f16)BIAS, (f16)0, (f16)0, (f16)0, (f16)0};
    *(f16x8*)(Bpack + (size_t)i * 16 + 0) = b0;
    *(f16x8*)(Bpack + (size_t)i * 16 + 8) = b1;
    aw[i]  = w;
    out[i] = FLT_MAX;                 // atomicMin target (graph-safe re-init)
}

__global__ void init_kernel(float* __restrict__ out, int n) {
    int i = blockIdx.x * blockDim.x + threadIdx.x;
    if (i < n) out[i] = FLT_MAX;
}

static __device__ __forceinline__ unsigned umin2(unsigned a, unsigned b) {
    return a < b ? a : b;
}

// 32x32x16 MFMA main kernel — R19 loop VERBATIM; only BSPLIT changed.
// LESSON R15: inline asm must never read MFMA results (silent corruption).
// LESSON R16: extra addressing VALU grows wall 1:1 (linear const offsets only).
// LESSON R17: too many live d-vectors -> AGPR shuffle tax.
// LESSON R18: MORE blocks (more epilogue replicas) = loss -> R22 tries FEWER.
// LESSON R20: PM=1 halves B-reuse = loss.
// LESSON R21: launch_bounds can't force accumulators out of AGPR homing;
//             footprint ~110 regs -> ~4.6 waves/SIMD regardless.
// R19 win: unsigned-domain fold (v_min3_u32 fuses legally).
// A operand: row = lane&31, k = (lane>>5)*8 + j.
// B operand: col = lane&31, k = (lane>>5)*8 + j.
// C/D: col = lane&31, row = (reg&3) + 8*(reg>>2) + 4*(lane>>5)  [m74/m101].
__global__ __launch_bounds__(THREADS, 4) void chamfer_mfma32(
    const float* __restrict__ xyz1,
    const float* __restrict__ xyz2,
    const f16*  __restrict__ Bpack,
    const float* __restrict__ aw,
    float* __restrict__ out)
{
    int bid = blockIdx.x;
    int dir   = bid & 1;   bid >>= 1;
    int bs    = bid & (BSPLIT - 1); bid >>= 1;   // log2(BSPLIT)=1
    int ab    = bid & 31;  bid >>= 5;   // N_/256 = 32 a-blocks
    int batch = bid;                    // 0..7

    const int lane = threadIdx.x & 63;
    const int wv   = threadIdx.x >> 6;
    const int g    = lane >> 5;         // k-half 0/1
    const int c    = lane & 31;         // a-row / b-col within tile

    const int aoff = dir ? NSIDE : 0;
    const int boff = dir ? 0 : NSIDE;
    const int abase = batch * N_ + ab * THREADS + wv * (PM * 32);

    const float* axyz = (dir ? xyz2 : xyz1);

    // ---- A fragments from raw f32 coords ----
    f16x8 af[PM];
#pragma unroll
    for (int t = 0; t < PM; ++t) {
        int pa = abase + t * 32 + c;
        const float* s = axyz + 3 * (size_t)pa;
        float x = s[0], y = s[1], z = s[2];
        f16 xh = (f16)x, yh = (f16)y, zh = (f16)z;
        f16 xl = (f16)(x - (float)xh);
        f16 yl = (f16)(y - (float)yh);
        f16 zl = (f16)(z - (float)zh);
        f16 x2 = (f16)(-2.0f * (float)xh), x2l = (f16)(-2.0f * (float)xl);
        f16 y2 = (f16)(-2.0f * (float)yh), y2l = (f16)(-2.0f * (float)yl);
        f16 z2 = (f16)(-2.0f * (float)zh), z2l = (f16)(-2.0f * (float)zl);
        f16x8 lo = {(f16)1.0f, (f16)1.0f, x2, x2, x2l, y2, y2, y2l};
        f16x8 hi = {z2, z2, z2l, (f16)1.0f, (f16)0, (f16)0, (f16)0, (f16)0};
        af[t] = (g == 0) ? lo : hi;
    }

    // ---- B-fragment stream: tile = 32 points x 16 f16 = 1 KB ----
    const f16* Bp = Bpack + (size_t)(boff + batch * M_ + bs * BCHUNK) * 16;
    const f16* blane = Bp + (size_t)c * 16 + g * 8;

    unsigned m[PM][16];
#pragma unroll
    for (int t = 0; t < PM; ++t)
#pragma unroll
        for (int i = 0; i < 16; ++i) m[t][i] = 0x7F7FFFFFu;  // FLT_MAX bits

    const f32x16 zero16 = {0.f,0.f,0.f,0.f,0.f,0.f,0.f,0.f,
                           0.f,0.f,0.f,0.f,0.f,0.f,0.f,0.f};

    // register prefetch depth 4 tiles; tail over-reads land in aw[] (valid ws)
    f16x8 b0 = *(const f16x8*)(blane + 0 * 512);
    f16x8 b1 = *(const f16x8*)(blane + 1 * 512);
    f16x8 b2 = *(const f16x8*)(blane + 2 * 512);
    f16x8 b3 = *(const f16x8*)(blane + 3 * 512);
    for (int it = 0; it < NTILE; it += 2) {
        f16x8 c0 = b0, c1 = b1;
        b0 = b2; b1 = b3;
        b2 = *(const f16x8*)(blane + (size_t)(it + 4) * 512);
        b3 = *(const f16x8*)(blane + (size_t)(it + 5) * 512);
#pragma unroll
        for (int t = 0; t < PM; ++t) {
            f32x16 d0 = __builtin_amdgcn_mfma_f32_32x32x16_f16(af[t], c0, zero16, 0, 0, 0);
            f32x16 d1 = __builtin_amdgcn_mfma_f32_32x32x16_f16(af[t], c1, zero16, 0, 0, 0);
#pragma unroll
            for (int i = 0; i < 16; ++i) {
                unsigned u0 = __float_as_uint(d0[i]);
                unsigned u1 = __float_as_uint(d1[i]);
                m[t][i] = umin2(m[t][i], umin2(u0, u1));  // -> v_min3_u32
            }
        }
    }

    // ---- Reduce min over the 32 col-lanes, then atomicMin ----
    const float* awp = aw + aoff;
    float* o = out + aoff;
#pragma unroll
    for (int t = 0; t < PM; ++t) {
        unsigned mm[16];
#pragma unroll
        for (int i = 0; i < 16; ++i) mm[i] = m[t][i];
#pragma unroll
        for (int s = 1; s < 32; s <<= 1) {
#pragma unroll
            for (int i = 0; i < 16; ++i)
                mm[i] = umin2(mm[i], (unsigned)__shfl_xor((int)mm[i], s));
        }
        // lane c (c<16) takes reg=c via static select chain (no dyn index)
        unsigned uval = mm[0];
#pragma unroll
        for (int r = 1; r < 16; ++r) uval = (c == r) ? mm[r] : uval;
        if (c < 16) {
            int row = abase + t * 32 + (c & 3) + 8 * (c >> 2) + 4 * g;
            float val = __uint_as_float(uval) - BIAS;     // bias removal exact
            float dd = fmaxf(awp[row] + val, 0.0f);       // clamp keeps uint-min valid
            atomicMin((unsigned int*)(o + row), __float_as_uint(dd));
        }
    }
}

// Fallback if ws too small: raw reads, scalar math (known-good from R2).
#define FP      8
#define FSPLIT  8
#define FCHUNK  (M_ / FSPLIT)
#define FAPB    (THREADS * FP)
#define FATILES (N_ / FAPB)
#define FNBLOCKS (2 * FSPLIT * FATILES * B_)
__global__ __launch_bounds__(THREADS) void chamfer_raw(
    const float* __restrict__ xyz1,
    const float* __restrict__ xyz2,
    float* __restrict__ out)
{
    int bid = blockIdx.x;
    int dir   = bid & 1;                 bid >>= 1;
    int chunk = bid & (FSPLIT - 1);      bid /= FSPLIT;
    int atile = bid & (FATILES - 1);     bid /= FATILES;
    int batch = bid;

    const float* A  = dir ? xyz2 : xyz1;
    const float* Bp = dir ? xyz1 : xyz2;
    float* o = out + (dir ? (B_ * N_) : 0);

    const int a0 = batch * N_ + atile * FAPB + threadIdx.x;

    float ax2[FP], ay2[FP], az2[FP], aww[FP], mm[FP];
#pragma unroll
    for (int p = 0; p < FP; ++p) {
        int idx = a0 + p * THREADS;
        float x = A[3 * idx + 0];
        float y = A[3 * idx + 1];
        float z = A[3 * idx + 2];
        ax2[p] = -2.0f * x;
        ay2[p] = -2.0f * y;
        az2[p] = -2.0f * z;
        aww[p] = fmaf(x, x, fmaf(y, y, z * z));
        mm[p]  = FLT_MAX;
    }

    const float* bp = Bp + 3 * (batch * M_ + chunk * FCHUNK);
#pragma unroll 2
    for (int j = 0; j < FCHUNK; j += 2) {
        float b0x = bp[3 * j + 0], b0y = bp[3 * j + 1], b0z = bp[3 * j + 2];
        float b1x = bp[3 * j + 3], b1y = bp[3 * j + 4], b1z = bp[3 * j + 5];
        float b0w = fmaf(b0x, b0x, fmaf(b0y, b0y, b0z * b0z));
        float b1w = fmaf(b1x, b1x, fmaf(b1y, b1y, b1z * b1z));
#pragma unroll
        for (int p = 0; p < FP; ++p) {
            float t0 = fmaf(ax2[p], b0x, b0w);
            t0 = fmaf(ay2[p], b0y, t0);
            t0 = fmaf(az2[p], b0z, t0);
            float t1 = fmaf(ax2[p], b1x, b1w);
            t1 = fmaf(ay2[p], b1y, t1);
            t1 = fmaf(az2[p], b1z, t1);
            mm[p] = fminf(mm[p], fminf(t0, t1));
        }
    }

#pragma unroll
    for (int p = 0; p < FP; ++p) {
        float d = fmaxf(aww[p] + mm[p], 0.0f);
        atomicMin((unsigned int*)(o + a0 + p * THREADS), __float_as_uint(d));
    }
}

extern "C" void kernel_launch(void* const* d_in, const int* in_sizes, int n_in,
                              void* d_out, int out_size, void* d_ws, size_t ws_size,
                              hipStream_t stream) {
    const float* xyz1 = (const float*)d_in[0];
    const float* xyz2 = (const float*)d_in[1];
    float* out = (float*)d_out;

    // ws layout: Bpack [NTOT*32B] @0, aw [NTOT*4B] after, +16KB pad for
    // prefetch tail over-read (lands in aw, valid memory).
    const size_t bpack_bytes = (size_t)NTOT * 32;
    const size_t need = bpack_bytes + (size_t)NTOT * 4 + 16384;
    if (ws_size >= need) {
        f16*   Bpack = (f16*)d_ws;
        float* aw    = (float*)((char*)d_ws + bpack_bytes);
        prep_kernel<<<(NTOT + 255) / 256, 256, 0, stream>>>(
            xyz1, xyz2, Bpack, aw, out, NSIDE, NTOT);
        chamfer_mfma32<<<NBLOCKS, THREADS, 0, stream>>>(xyz1, xyz2, Bpack, aw, out);
    } else {
        init_kernel<<<(NTOT + 255) / 256, 256, 0, stream>>>(out, NTOT);
        chamfer_raw<<<FNBLOCKS, THREADS, 0, stream>>>(xyz1, xyz2, out);
    }
}